// Round 2
// baseline (656.843 us; speedup 1.0000x reference)
//
#include <hip/hip_runtime.h>

typedef unsigned short u16;
typedef short bf16x8 __attribute__((ext_vector_type(8)));   // 8 bf16 = 4 VGPRs
typedef u16 u16x8 __attribute__((ext_vector_type(8)));
typedef float f32x16 __attribute__((ext_vector_type(16)));

__device__ __forceinline__ u16 f2bf_rne(float f) {
  unsigned u = __builtin_bit_cast(unsigned, f);
  unsigned r = (u + 0x7fffu + ((u >> 16) & 1u)) >> 16;   // RNE; values are tame
  return (u16)r;
}

#define GLDS16(g, l) __builtin_amdgcn_global_load_lds(                        \
    (const __attribute__((address_space(1))) unsigned int*)(g),               \
    (__attribute__((address_space(3))) unsigned int*)(l), 16, 0, 0)

#define NKP 64   // K panels of 32

// ---- W2 -> interleaved trunc-hi/lo bf16, tile-linear, XOR-swizzled ----
// bf16 idx i = [nt(1)][kp(6)][col(8)][phys(3)][jj(3)]
// data slot s_hl = phys ^ (col&7); s = s_hl>>1 (k-chunk), hl = s_hl&1 (hi/lo)
__global__ void k_w2prep(const float* __restrict__ W2, u16* __restrict__ dst) {
  int i = blockIdx.x * blockDim.x + threadIdx.x;   // 0 .. 2^21-1
  int jj  = i & 7;
  int ph  = (i >> 3) & 7;
  int col = (i >> 6) & 255;
  int kp  = (i >> 14) & 63;
  int nt  = (i >> 20) & 1;
  int s_hl = ph ^ (col & 7);
  int f = (kp << 5) + ((s_hl >> 1) << 3) + jj;
  int e = (nt << 8) + col;
  float v = W2[(e << 11) + f];
  unsigned u = __builtin_bit_cast(unsigned, v);
  u16 r;
  if ((s_hl & 1) == 0) {
    r = (u16)(u >> 16);                               // truncated hi
  } else {
    float hi = __builtin_bit_cast(float, u & 0xffff0000u);
    r = f2bf_rne(v - hi);                             // exact remainder, RNE
  }
  dst[i] = r;
}

// ---- main fused kernel ----
// out[t][e] = sum_f relu(b1[f] + sum_q cos(x[t][q])cos(th[q])*W1[f][q]) * W2[e][f] + b2[e]
// GEMM M=32768 N=512 K=2048. BM=128 BN=256 BK=32. 512 thr (8 waves 2Mx4N),
// wave tile 64x64 via 2x2 mfma_f32_32x32x16_bf16, 3-term split-bf16.
// LDS 80KB: A 16KB single-buffer (H written in-loop), B 2x32KB double-buffer.
__global__ __launch_bounds__(512, 4) void k_ffq(
    const float* __restrict__ x, const float* __restrict__ theta,
    const u16* __restrict__ w2arr,
    const float* __restrict__ W1, const float* __restrict__ b1,
    const float* __restrict__ b2, float* __restrict__ out)
{
  extern __shared__ char smem[];
  char* sA  = smem;            // 16384 B: [row(128)][128B = 8 phys 16B slots]
  char* sB0 = smem + 16384;    // 32768 B: [col(256)][128B]
  char* sB1 = smem + 49152;    // 32768 B

  const int tid  = threadIdx.x;
  const int lane = tid & 63;
  const int wid  = tid >> 6;
  const int nt = blockIdx.x & 1;
  const int mt = blockIdx.x >> 1;

  // ---- quantum layer for this lane's owned H row (regs for whole kernel)
  const int hs   = tid & 3;          // k-chunk 0..3
  const int hrow = tid >> 2;         // 0..127
  float qr[8];
  {
    const float4* xp = (const float4*)(x + (size_t)((mt << 7) + hrow) * 512);
    const float4 x0 = xp[0], x1 = xp[1];
    const float4* tp = (const float4*)theta;
    const float4 t0 = tp[0], t1 = tp[1];
    qr[0] = cosf(x0.x) * cosf(t0.x);
    qr[1] = cosf(x0.y) * cosf(t0.y);
    qr[2] = cosf(x0.z) * cosf(t0.z);
    qr[3] = cosf(x0.w) * cosf(t0.w);
    qr[4] = cosf(x1.x) * cosf(t1.x);
    qr[5] = cosf(x1.y) * cosf(t1.y);
    qr[6] = cosf(x1.z) * cosf(t1.z);
    qr[7] = cosf(x1.w) * cosf(t1.w);
  }
  const int wAh = (hrow << 7) + (((hs << 1) ^ (hrow & 7)) << 4);
  const int wAl = wAh ^ 16;

  // ---- MFMA fragment LDS offsets (32x32x16: lane -> row=l&31, k-half=l>>5)
  const int wr = wid >> 2;           // 0..1
  const int wc = wid & 3;            // 0..3
  const int l31 = lane & 31;
  const int s0  = lane >> 5;         // 0..1
  const int arow0 = (wr << 6) | l31;
  const int arow1 = arow0 | 32;
  const int aoff0 = (arow0 << 7) + (((s0 << 1) ^ (arow0 & 7)) << 4);
  const int aoff1 = (arow1 << 7) + (((s0 << 1) ^ (arow1 & 7)) << 4);
  const int bcol0 = (wc << 6) | l31;
  const int bcol1 = bcol0 | 32;
  const int boff0 = (bcol0 << 7) + (((s0 << 1) ^ (bcol0 & 7)) << 4);
  const int boff1 = (bcol1 << 7) + (((s0 << 1) ^ (bcol1 & 7)) << 4);

  f32x16 acc00 = (f32x16)0.0f, acc01 = (f32x16)0.0f;
  f32x16 acc10 = (f32x16)0.0f, acc11 = (f32x16)0.0f;

  u16x8 hi8n, lo8n;
  auto computeH = [&](int kt) {
    const int f0 = (kt << 5) + (hs << 3);
    const float4* b1p = (const float4*)(b1 + f0);
    const float4 bva = b1p[0], bvb = b1p[1];
    const float bb[8] = {bva.x, bva.y, bva.z, bva.w, bvb.x, bvb.y, bvb.z, bvb.w};
    float h[8];
#pragma unroll
    for (int r = 0; r < 8; ++r) {
      const float4* wp = (const float4*)(W1 + ((f0 + r) << 3));
      const float4 wa = wp[0], wb = wp[1];
      float s = bb[r];
      s = fmaf(qr[0], wa.x, s); s = fmaf(qr[1], wa.y, s);
      s = fmaf(qr[2], wa.z, s); s = fmaf(qr[3], wa.w, s);
      s = fmaf(qr[4], wb.x, s); s = fmaf(qr[5], wb.y, s);
      s = fmaf(qr[6], wb.z, s); s = fmaf(qr[7], wb.w, s);
      h[r] = fmaxf(s, 0.f);
    }
#pragma unroll
    for (int r = 0; r < 8; ++r) {
      unsigned u = __builtin_bit_cast(unsigned, h[r]);
      hi8n[r] = (u16)(u >> 16);
      float hif = __builtin_bit_cast(float, u & 0xffff0000u);
      lo8n[r] = f2bf_rne(h[r] - hif);
    }
  };

  auto stageB = [&](int kt, char* dst) {
    const char* src = (const char*)w2arr + ((size_t)((nt << 6) + kt) << 15);
#pragma unroll
    for (int i = 0; i < 4; ++i) {
      const int off = ((i << 3) | wid) << 10;     // 32 chunks of 1 KB
      GLDS16(src + off + lane * 16, dst + off);
    }
  };

  // ---- prologue: stage B(0), compute+write A(0)
  stageB(0, sB0);
  computeH(0);
  *(u16x8*)(sA + wAh) = hi8n;
  *(u16x8*)(sA + wAl) = lo8n;
  __syncthreads();

  for (int kp = 0; kp < NKP; ++kp) {
    char* sBc = (kp & 1) ? sB1 : sB0;
    char* sBn = (kp & 1) ? sB0 : sB1;
    const bool pre = (kp < NKP - 1);
    if (pre) {
      stageB(kp + 1, sBn);      // into free buffer; drained by this iter's barrier
      computeH(kp + 1);         // VALU, overlaps other waves' MFMA
    }
    __builtin_amdgcn_s_setprio(1);
#pragma unroll
    for (int ks = 0; ks < 2; ++ks) {
      const int kx = ks << 6;   // k-step 1 lives 4 phys slots (64 B) away, XOR-able
      bf16x8 a0h = *(const bf16x8*)(sA + (aoff0 ^ kx));
      bf16x8 a0l = *(const bf16x8*)(sA + (aoff0 ^ kx ^ 16));
      bf16x8 a1h = *(const bf16x8*)(sA + (aoff1 ^ kx));
      bf16x8 a1l = *(const bf16x8*)(sA + (aoff1 ^ kx ^ 16));
      {
        bf16x8 bh = *(const bf16x8*)(sBc + (boff0 ^ kx));
        bf16x8 bl = *(const bf16x8*)(sBc + (boff0 ^ kx ^ 16));
        acc00 = __builtin_amdgcn_mfma_f32_32x32x16_bf16(a0h, bh, acc00, 0, 0, 0);
        acc10 = __builtin_amdgcn_mfma_f32_32x32x16_bf16(a1h, bh, acc10, 0, 0, 0);
        acc00 = __builtin_amdgcn_mfma_f32_32x32x16_bf16(a0l, bh, acc00, 0, 0, 0);
        acc10 = __builtin_amdgcn_mfma_f32_32x32x16_bf16(a1l, bh, acc10, 0, 0, 0);
        acc00 = __builtin_amdgcn_mfma_f32_32x32x16_bf16(a0h, bl, acc00, 0, 0, 0);
        acc10 = __builtin_amdgcn_mfma_f32_32x32x16_bf16(a1h, bl, acc10, 0, 0, 0);
      }
      {
        bf16x8 bh = *(const bf16x8*)(sBc + (boff1 ^ kx));
        bf16x8 bl = *(const bf16x8*)(sBc + (boff1 ^ kx ^ 16));
        acc01 = __builtin_amdgcn_mfma_f32_32x32x16_bf16(a0h, bh, acc01, 0, 0, 0);
        acc11 = __builtin_amdgcn_mfma_f32_32x32x16_bf16(a1h, bh, acc11, 0, 0, 0);
        acc01 = __builtin_amdgcn_mfma_f32_32x32x16_bf16(a0l, bh, acc01, 0, 0, 0);
        acc11 = __builtin_amdgcn_mfma_f32_32x32x16_bf16(a1l, bh, acc11, 0, 0, 0);
        acc01 = __builtin_amdgcn_mfma_f32_32x32x16_bf16(a0h, bl, acc01, 0, 0, 0);
        acc11 = __builtin_amdgcn_mfma_f32_32x32x16_bf16(a1h, bl, acc11, 0, 0, 0);
      }
    }
    __builtin_amdgcn_s_setprio(0);
    if (pre) {
      __syncthreads();                    // all A reads of kp done (also drains vmcnt)
      *(u16x8*)(sA + wAh) = hi8n;         // A(kp+1)
      *(u16x8*)(sA + wAl) = lo8n;
      __syncthreads();                    // A writes visible, B(kp+1) landed
    }
  }

  // ---- epilogue: 32x32 C/D layout col=lane&31, row=(rg&3)+8*(rg>>2)+4*(lane>>5)
  const int gcol_base = (nt << 8) | (wc << 6) | l31;
  const int grow_base = (mt << 7) | (wr << 6) | (s0 << 2);

#define STORE_FRAG(A, MI, NI) do {                                          \
    const int col = gcol_base + ((NI) << 5);                                \
    const float bv = b2[col];                                               \
    float* op = out + (size_t)(grow_base + ((MI) << 5)) * 512 + col;        \
    _Pragma("unroll")                                                       \
    for (int rg = 0; rg < 16; ++rg) {                                       \
      const int rr = (rg & 3) + ((rg >> 2) << 3);                           \
      op[(size_t)rr * 512] = A[rg] + bv;                                    \
    }                                                                       \
  } while (0)

  STORE_FRAG(acc00, 0, 0); STORE_FRAG(acc01, 0, 1);
  STORE_FRAG(acc10, 1, 0); STORE_FRAG(acc11, 1, 1);
#undef STORE_FRAG
}

extern "C" void kernel_launch(void* const* d_in, const int* in_sizes, int n_in,
                              void* d_out, int out_size, void* d_ws, size_t ws_size,
                              hipStream_t stream) {
  const float* x     = (const float*)d_in[0];
  const float* theta = (const float*)d_in[1];
  const float* W1    = (const float*)d_in[2];
  const float* b1    = (const float*)d_in[3];
  const float* W2    = (const float*)d_in[4];
  const float* b2    = (const float*)d_in[5];
  float* out = (float*)d_out;

  const int M = in_sizes[0] / 512;                 // 32768 tokens
  u16* w2arr = (u16*)d_ws;                         // 4 MiB

  k_w2prep<<<(1 << 21) / 256, 256, 0, stream>>>(W2, w2arr);
  k_ffq<<<dim3((M / 128) * 2), 512, 81920, stream>>>(x, theta, w2arr, W1, b1, b2, out);
}

// Round 5
// 344.591 us; speedup vs baseline: 1.9062x; 1.9062x over previous
//
#include <hip/hip_runtime.h>

typedef unsigned short u16;
typedef short bf16x8 __attribute__((ext_vector_type(8)));   // 8 bf16 = 4 VGPRs
typedef u16 u16x8 __attribute__((ext_vector_type(8)));
typedef float f32x4 __attribute__((ext_vector_type(4)));

__device__ __forceinline__ u16 f2bf_rne(float f) {
  unsigned u = __builtin_bit_cast(unsigned, f);
  unsigned r = (u + 0x7fffu + ((u >> 16) & 1u)) >> 16;   // RNE; values are tame
  return (u16)r;
}
__device__ __forceinline__ float bf2f(u16 h) {
  unsigned u = ((unsigned)h) << 16;
  return __builtin_bit_cast(float, u);
}

#define GLDS16(g, l) __builtin_amdgcn_global_load_lds(                        \
    (const __attribute__((address_space(1))) unsigned int*)(g),               \
    (__attribute__((address_space(3))) unsigned int*)(l), 16, 0, 0)

#define NKP 64   // K panels of 32

// ---- W2 -> RNE hi/lo bf16, tile-linear, slot-XOR swizzled ----
// bf16 idx i = [nt(2)][kp(6)][col(7)][ph(3)][jj(3)]   (2^21 elems, 4 MiB)
// data slot s_hl = ph ^ (col&7); kq = s_hl>>1, hl = s_hl&1; f = kp*32+kq*8+jj
__global__ void k_w2prep(const float* __restrict__ W2, u16* __restrict__ dst) {
  int i = blockIdx.x * blockDim.x + threadIdx.x;
  int jj  = i & 7;
  int ph  = (i >> 3) & 7;
  int col = (i >> 6) & 127;
  int kp  = (i >> 13) & 63;
  int nt  = (i >> 19) & 3;
  int s_hl = ph ^ (col & 7);
  int f = (kp << 5) + ((s_hl >> 1) << 3) + jj;
  int e = (nt << 7) + col;
  float v = W2[(e << 11) + f];
  u16 hi = f2bf_rne(v);
  dst[i] = (s_hl & 1) ? f2bf_rne(v - bf2f(hi)) : hi;
}

// ---- main fused kernel ----
// GEMM M=32768 N=512 K=2048. BM=BN=128 BK=32. 256 thr (4 waves 2x2),
// wave tile 64x64 via 4x4 mfma_f32_16x16x32_bf16 frags, 3-term split-bf16.
// LDS 48KB: A 16KB single (H recomputed per panel, scalar-cache W1), B 2x16KB dbuf.
__global__ __launch_bounds__(256, 3) void k_ffq(
    const float* __restrict__ x, const float* __restrict__ theta,
    const u16* __restrict__ w2arr,
    const float* __restrict__ W1, const float* __restrict__ b1,
    const float* __restrict__ b2, float* __restrict__ out)
{
  __shared__ __align__(16) char smem[49152];
  char* sA  = smem;            // [row(128)][8 slots x 16B]; slot s_hl=(kq<<1)|hl at phys s_hl^(row&7)
  char* sB0 = smem + 16384;    // [col(128)][same]
  char* sB1 = smem + 32768;

  const int tid  = threadIdx.x;
  const int lane = tid & 63;
  const int wid  = tid >> 6;
  const int nt = blockIdx.x & 3;
  const int mt = blockIdx.x >> 2;

  // ---- H role: wave -> (t-half, f-octet-pair); lane -> token
  const int myt = ((wid & 1) << 6) | lane;                       // 0..127
  const int fo0 = __builtin_amdgcn_readfirstlane((wid >> 1) << 1);  // wave-uniform octet
  // quantum layer: q values in regs for whole kernel
  float qr[8];
  {
    const float4* xp = (const float4*)(x + (size_t)((mt << 7) + myt) * 512);
    const float4 x0 = xp[0], x1 = xp[1];
    const float4* tp = (const float4*)theta;
    const float4 t0 = tp[0], t1 = tp[1];
    qr[0] = cosf(x0.x) * cosf(t0.x);  qr[1] = cosf(x0.y) * cosf(t0.y);
    qr[2] = cosf(x0.z) * cosf(t0.z);  qr[3] = cosf(x0.w) * cosf(t0.w);
    qr[4] = cosf(x1.x) * cosf(t1.x);  qr[5] = cosf(x1.y) * cosf(t1.y);
    qr[6] = cosf(x1.z) * cosf(t1.z);  qr[7] = cosf(x1.w) * cosf(t1.w);
  }
  const int wA0 = (myt << 7) + ((((fo0 + 0) << 1) ^ (myt & 7)) << 4);
  const int wA1 = (myt << 7) + ((((fo0 + 1) << 1) ^ (myt & 7)) << 4);

  // ---- GEMM roles
  const int wr = wid >> 1, wc = wid & 1;
  const int l15 = lane & 15;
  const int kq  = lane >> 4;            // k-octet 0..3

  f32x4 acc[4][4];
#pragma unroll
  for (int i = 0; i < 4; ++i)
#pragma unroll
    for (int j = 0; j < 4; ++j) acc[i][j] = (f32x4){0.f, 0.f, 0.f, 0.f};

  // H for one octet: 8 rows of W1 at wave-uniform addresses -> scalar cache
  u16x8 hA0, lA0, hA1, lA1;
  auto computeH = [&](int kt, int o, u16x8& hi8, u16x8& lo8) {
    const int f0 = (kt << 5) + (o << 3);
    const float* __restrict__ bp = b1 + f0;
    float h[8];
#pragma unroll
    for (int r = 0; r < 8; ++r) {
      const float* __restrict__ wp = W1 + ((f0 + r) << 3);   // wave-uniform
      float s = bp[r];
      s = fmaf(qr[0], wp[0], s); s = fmaf(qr[1], wp[1], s);
      s = fmaf(qr[2], wp[2], s); s = fmaf(qr[3], wp[3], s);
      s = fmaf(qr[4], wp[4], s); s = fmaf(qr[5], wp[5], s);
      s = fmaf(qr[6], wp[6], s); s = fmaf(qr[7], wp[7], s);
      h[r] = fmaxf(s, 0.f);
    }
#pragma unroll
    for (int r = 0; r < 8; ++r) {
      u16 hb = f2bf_rne(h[r]);
      hi8[r] = hb;
      lo8[r] = f2bf_rne(h[r] - bf2f(hb));
    }
  };

  auto stageB = [&](int kt, char* dst) {
    const char* src = (const char*)w2arr + ((size_t)((nt << 6) + kt) << 14);
#pragma unroll
    for (int i = 0; i < 4; ++i) {
      const int off = ((i << 2) | wid) << 10;     // 16 chunks of 1 KB
      GLDS16(src + off + lane * 16, dst + off);
    }
  };

  // ---- prologue
  stageB(0, sB0);
  computeH(0, fo0, hA0, lA0);
  computeH(0, fo0 + 1, hA1, lA1);
  *(u16x8*)(sA + wA0) = hA0;  *(u16x8*)(sA + (wA0 ^ 16)) = lA0;
  *(u16x8*)(sA + wA1) = hA1;  *(u16x8*)(sA + (wA1 ^ 16)) = lA1;
  __syncthreads();   // drains vmcnt (B0) + lds writes

  for (int kp = 0; kp < NKP; ++kp) {
    char* sBc = (kp & 1) ? sB1 : sB0;
    char* sBn = (kp & 1) ? sB0 : sB1;
    const bool pre = (kp < NKP - 1);
    if (pre) {
      stageB(kp + 1, sBn);                 // overlaps MFMA below
      computeH(kp + 1, fo0, hA0, lA0);     // scalar W1, VALU overlaps MFMA
      computeH(kp + 1, fo0 + 1, hA1, lA1);
    }
    __builtin_amdgcn_s_setprio(1);
    bf16x8 ah[4], al[4];
#pragma unroll
    for (int mi = 0; mi < 4; ++mi) {
      const int arow = (wr << 6) | (mi << 4) | l15;
      const int ao = (arow << 7) + (((kq << 1) ^ (arow & 7)) << 4);
      ah[mi] = *(const bf16x8*)(sA + ao);
      al[mi] = *(const bf16x8*)(sA + (ao ^ 16));
    }
#pragma unroll
    for (int ni = 0; ni < 4; ++ni) {
      const int bcol = (wc << 6) | (ni << 4) | l15;
      const int bo = (bcol << 7) + (((kq << 1) ^ (bcol & 7)) << 4);
      const bf16x8 bh = *(const bf16x8*)(sBc + bo);
      const bf16x8 bl = *(const bf16x8*)(sBc + (bo ^ 16));
#pragma unroll
      for (int mi = 0; mi < 4; ++mi) {
        acc[mi][ni] = __builtin_amdgcn_mfma_f32_16x16x32_bf16(ah[mi], bh, acc[mi][ni], 0, 0, 0);
        acc[mi][ni] = __builtin_amdgcn_mfma_f32_16x16x32_bf16(al[mi], bh, acc[mi][ni], 0, 0, 0);
        acc[mi][ni] = __builtin_amdgcn_mfma_f32_16x16x32_bf16(ah[mi], bl, acc[mi][ni], 0, 0, 0);
      }
    }
    __builtin_amdgcn_s_setprio(0);
    if (pre) {
      __syncthreads();                     // A reads of kp done; B(kp+1) landed
      *(u16x8*)(sA + wA0) = hA0;  *(u16x8*)(sA + (wA0 ^ 16)) = lA0;
      *(u16x8*)(sA + wA1) = hA1;  *(u16x8*)(sA + (wA1 ^ 16)) = lA1;
      __syncthreads();                     // A(kp+1) visible
    }
  }

  // ---- epilogue: 16x16 C/D layout col=lane&15, row=(lane>>4)*4+r (m89-verified)
#pragma unroll
  for (int ni = 0; ni < 4; ++ni) {
    const int col = (nt << 7) | (wc << 6) | (ni << 4) | l15;
    const float bv = b2[col];
#pragma unroll
    for (int mi = 0; mi < 4; ++mi) {
      const int row0 = (mt << 7) | (wr << 6) | (mi << 4) | (kq << 2);
      float* op = out + (size_t)row0 * 512 + col;
#pragma unroll
      for (int r = 0; r < 4; ++r)
        op[(size_t)r * 512] = acc[mi][ni][r] + bv;
    }
  }
}

extern "C" void kernel_launch(void* const* d_in, const int* in_sizes, int n_in,
                              void* d_out, int out_size, void* d_ws, size_t ws_size,
                              hipStream_t stream) {
  const float* x     = (const float*)d_in[0];
  const float* theta = (const float*)d_in[1];
  const float* W1    = (const float*)d_in[2];
  const float* b1    = (const float*)d_in[3];
  const float* W2    = (const float*)d_in[4];
  const float* b2    = (const float*)d_in[5];
  float* out = (float*)d_out;

  const int M = in_sizes[0] / 512;                 // 32768 tokens
  u16* w2arr = (u16*)d_ws;                         // 4 MiB

  k_w2prep<<<(1 << 21) / 256, 256, 0, stream>>>(W2, w2arr);
  k_ffq<<<dim3((M / 128) * 4), 256, 0, stream>>>(x, theta, w2arr, W1, b1, b2, out);
}

// Round 6
// 288.338 us; speedup vs baseline: 2.2780x; 1.1951x over previous
//
#include <hip/hip_runtime.h>

typedef unsigned short u16;
typedef short bf16x8 __attribute__((ext_vector_type(8)));   // 8 bf16 = 4 VGPRs
typedef u16 u16x8 __attribute__((ext_vector_type(8)));
typedef float f32x4 __attribute__((ext_vector_type(4)));

__device__ __forceinline__ u16 f2bf_rne(float f) {
  unsigned u = __builtin_bit_cast(unsigned, f);
  unsigned r = (u + 0x7fffu + ((u >> 16) & 1u)) >> 16;   // RNE; values are tame
  return (u16)r;
}

#define GLDS16(g, l) __builtin_amdgcn_global_load_lds(                        \
    (const __attribute__((address_space(1))) unsigned int*)(g),               \
    (__attribute__((address_space(3))) unsigned int*)(l), 16, 0, 0)

#define NKP 32   // K panels of 64

// ---- W2 -> RNE bf16, tile-linear, slot-XOR swizzled ----
// bf16 idx i = [nt(2)][kp(5)][col(7)][ph(3)][jj(3)]   (2^20 elems, 2 MiB)
// data octet o = ph ^ (col&7); f = kp*64 + o*8 + jj; e = nt*128 + col
__global__ void k_w2prep(const float* __restrict__ W2, u16* __restrict__ dst) {
  int i = blockIdx.x * blockDim.x + threadIdx.x;
  int jj  = i & 7;
  int ph  = (i >> 3) & 7;
  int col = (i >> 6) & 127;
  int kp  = (i >> 13) & 31;
  int nt  = (i >> 18) & 3;
  int f = (kp << 6) + ((ph ^ (col & 7)) << 3) + jj;
  int e = (nt << 7) + col;
  dst[i] = f2bf_rne(W2[(e << 11) + f]);
}

// ---- main fused kernel ----
// GEMM M=32768 N=512 K=2048, plain bf16 MFMA (RNE inputs, f32 accum).
// BM=BN=128 BK=64. 256 thr (4 waves 2x2), wave tile 64x64 via 4x4 16x16x32 frags.
// LDS 48KB: A 16KB single (H computed in-loop, scalar-cache W1), B 2x16KB dbuf.
// Per-panel order: stage B(kp+1) -> MFMA(kp) -> computeH(kp+1) -> bar -> writeA -> bar.
__global__ __launch_bounds__(256, 3) void k_ffq(
    const float* __restrict__ x, const float* __restrict__ theta,
    const u16* __restrict__ w2arr,
    const float* __restrict__ W1, const float* __restrict__ b1,
    const float* __restrict__ b2, float* __restrict__ out)
{
  __shared__ __align__(16) char smem[49152];
  char* sA  = smem;            // [row(128)][8 phys x 16B]; octet o at phys o^(row&7)
  char* sB0 = smem + 16384;    // [col(128)][same]
  char* sB1 = smem + 32768;

  const int tid  = threadIdx.x;
  const int lane = tid & 63;
  const int wid  = tid >> 6;
  const int nt = blockIdx.x & 3;
  const int mt = blockIdx.x >> 2;

  // ---- H role: wave -> (t-half, 4-octet group); lane -> token
  const int myt = ((wid & 1) << 6) | lane;                          // 0..127
  const int fo0 = __builtin_amdgcn_readfirstlane((wid >> 1) << 2);  // 0 or 4
  float qr[8];
  {
    const float4* xp = (const float4*)(x + (size_t)((mt << 7) + myt) * 512);
    const float4 x0 = xp[0], x1 = xp[1];
    const float4* tp = (const float4*)theta;
    const float4 t0 = tp[0], t1 = tp[1];
    qr[0] = cosf(x0.x) * cosf(t0.x);  qr[1] = cosf(x0.y) * cosf(t0.y);
    qr[2] = cosf(x0.z) * cosf(t0.z);  qr[3] = cosf(x0.w) * cosf(t0.w);
    qr[4] = cosf(x1.x) * cosf(t1.x);  qr[5] = cosf(x1.y) * cosf(t1.y);
    qr[6] = cosf(x1.z) * cosf(t1.z);  qr[7] = cosf(x1.w) * cosf(t1.w);
  }
  int wA[4];
#pragma unroll
  for (int g = 0; g < 4; ++g)
    wA[g] = (myt << 7) + (((fo0 + g) ^ (myt & 7)) << 4);

  // ---- GEMM roles
  const int wr = wid >> 1, wc = wid & 1;
  const int l15 = lane & 15;
  const int kq  = lane >> 4;            // k-octet-within-32 0..3

  f32x4 acc[4][4];
#pragma unroll
  for (int i = 0; i < 4; ++i)
#pragma unroll
    for (int j = 0; j < 4; ++j) acc[i][j] = (f32x4){0.f, 0.f, 0.f, 0.f};

  // H for this lane: 4 octets x 8 values; W1/b1 at wave-uniform addrs -> s_load
  u16x8 hN[4];
  auto computeH = [&](int kt) {
#pragma unroll
    for (int g = 0; g < 4; ++g) {
      const int f0 = (kt << 6) + ((fo0 + g) << 3);
      const float* __restrict__ bp = b1 + f0;
#pragma unroll
      for (int r = 0; r < 8; ++r) {
        const float* __restrict__ wp = W1 + ((f0 + r) << 3);   // wave-uniform
        float s = bp[r];
        s = fmaf(qr[0], wp[0], s); s = fmaf(qr[1], wp[1], s);
        s = fmaf(qr[2], wp[2], s); s = fmaf(qr[3], wp[3], s);
        s = fmaf(qr[4], wp[4], s); s = fmaf(qr[5], wp[5], s);
        s = fmaf(qr[6], wp[6], s); s = fmaf(qr[7], wp[7], s);
        hN[g][r] = f2bf_rne(fmaxf(s, 0.f));
      }
    }
  };

  auto writeA = [&]() {
#pragma unroll
    for (int g = 0; g < 4; ++g)
      *(u16x8*)(sA + wA[g]) = hN[g];
  };

  auto stageB = [&](int kt, char* dst) {
    const char* src = (const char*)w2arr + ((size_t)((nt << 5) + kt) << 14);
#pragma unroll
    for (int i = 0; i < 4; ++i) {
      const int off = ((i << 2) | wid) << 10;     // 16 chunks of 1 KB
      GLDS16(src + off + lane * 16, dst + off);
    }
  };

  // ---- prologue
  stageB(0, sB0);
  computeH(0);
  writeA();
  __syncthreads();   // drains vmcnt (B0) + lds writes

  for (int kp = 0; kp < NKP; ++kp) {
    char* sBc = (kp & 1) ? sB1 : sB0;
    char* sBn = (kp & 1) ? sB0 : sB1;
    const bool pre = (kp < NKP - 1);
    if (pre) stageB(kp + 1, sBn);        // issue early; lands under MFMA+H
    __builtin_amdgcn_s_setprio(1);
#pragma unroll
    for (int ks = 0; ks < 2; ++ks) {
      const int o = (ks << 2) | kq;      // octet 0..7
      bf16x8 ah[4];
#pragma unroll
      for (int mi = 0; mi < 4; ++mi) {
        const int arow = (wr << 6) | (mi << 4) | l15;
        ah[mi] = *(const bf16x8*)(sA + (arow << 7) + ((o ^ (arow & 7)) << 4));
      }
#pragma unroll
      for (int ni = 0; ni < 4; ++ni) {
        const int bcol = (wc << 6) | (ni << 4) | l15;
        const bf16x8 bh = *(const bf16x8*)(sBc + (bcol << 7) + ((o ^ (bcol & 7)) << 4));
#pragma unroll
        for (int mi = 0; mi < 4; ++mi)
          acc[mi][ni] = __builtin_amdgcn_mfma_f32_16x16x32_bf16(ah[mi], bh, acc[mi][ni], 0, 0, 0);
      }
    }
    __builtin_amdgcn_s_setprio(0);
    if (pre) {
      computeH(kp + 1);                  // VALU overlaps in-flight MFMAs
      __syncthreads();                   // A reads of kp done; B(kp+1) landed
      writeA();                          // A(kp+1)
      __syncthreads();                   // A(kp+1) visible
    }
  }

  // ---- epilogue: 16x16 C/D layout col=lane&15, row=(lane>>4)*4+r (m89-verified)
#pragma unroll
  for (int ni = 0; ni < 4; ++ni) {
    const int col = (nt << 7) | (wc << 6) | (ni << 4) | l15;
    const float bv = b2[col];
#pragma unroll
    for (int mi = 0; mi < 4; ++mi) {
      const int row0 = (mt << 7) | (wr << 6) | (mi << 4) | (kq << 2);
      float* op = out + (size_t)row0 * 512 + col;
#pragma unroll
      for (int r = 0; r < 4; ++r)
        op[(size_t)r * 512] = acc[mi][ni][r] + bv;
    }
  }
}

extern "C" void kernel_launch(void* const* d_in, const int* in_sizes, int n_in,
                              void* d_out, int out_size, void* d_ws, size_t ws_size,
                              hipStream_t stream) {
  const float* x     = (const float*)d_in[0];
  const float* theta = (const float*)d_in[1];
  const float* W1    = (const float*)d_in[2];
  const float* b1    = (const float*)d_in[3];
  const float* W2    = (const float*)d_in[4];
  const float* b2    = (const float*)d_in[5];
  float* out = (float*)d_out;

  const int M = in_sizes[0] / 512;                 // 32768 tokens
  u16* w2arr = (u16*)d_ws;                         // 2 MiB

  k_w2prep<<<(1 << 20) / 256, 256, 0, stream>>>(W2, w2arr);
  k_ffq<<<dim3((M / 128) * 4), 256, 0, stream>>>(x, theta, w2arr, W1, b1, b2, out);
}

// Round 8
// 250.572 us; speedup vs baseline: 2.6214x; 1.1507x over previous
//
#include <hip/hip_runtime.h>

typedef unsigned short u16;
typedef short bf16x8 __attribute__((ext_vector_type(8)));   // 8 bf16 = 4 VGPRs
typedef u16 u16x8 __attribute__((ext_vector_type(8)));
typedef float f32x4 __attribute__((ext_vector_type(4)));

__device__ __forceinline__ u16 f2bf_rne(float f) {
  unsigned u = __builtin_bit_cast(unsigned, f);
  unsigned r = (u + 0x7fffu + ((u >> 16) & 1u)) >> 16;   // RNE; values are tame
  return (u16)r;
}

#define GLDS16(g, l) __builtin_amdgcn_global_load_lds(                        \
    (const __attribute__((address_space(1))) unsigned int*)(g),               \
    (__attribute__((address_space(3))) unsigned int*)(l), 16, 0, 0)

// ---- W2 -> RNE bf16, tile-linear, slot-XOR swizzled (same layout as R6) ----
// bf16 idx i = [nt(2)][kp(5)][col(7)][ph(3)][jj(3)]   (2^20 elems, 2 MiB)
// data octet o = ph ^ (col&7); f = kp*64 + o*8 + jj; e = nt*128 + col
__global__ void k_w2prep(const float* __restrict__ W2, u16* __restrict__ dst) {
  int i = blockIdx.x * blockDim.x + threadIdx.x;
  int jj  = i & 7;
  int ph  = (i >> 3) & 7;
  int col = (i >> 6) & 127;
  int kp  = (i >> 13) & 31;
  int nt  = (i >> 18) & 3;
  int f = (kp << 6) + ((ph ^ (col & 7)) << 3) + jj;
  int e = (nt << 7) + col;
  dst[i] = f2bf_rne(W2[(e << 11) + f]);
}

// ---- layer 1: H'[oct][tok][8] bf16, octet-major (coalesced stores) ----
// h = relu(b1[f] + sum_q cos(x[t][q])cos(th[q]) * W1[f][q]); oct = f>>3.
// Block: 64 tokens x full F. Wave w: octets [w*64, w*64+64). Lane: token.
// W1/b1 addrs wave-uniform -> scalar cache (s_load), no L1-vector traffic.
__global__ __launch_bounds__(256) void k_h(
    const float* __restrict__ x, const float* __restrict__ theta,
    const float* __restrict__ W1, const float* __restrict__ b1,
    u16* __restrict__ Hws, int mbase, int chunkM)
{
  const int lane = threadIdx.x & 63;
  const int w    = threadIdx.x >> 6;
  const int tok  = (blockIdx.x << 6) + lane;            // within chunk
  const int obase = __builtin_amdgcn_readfirstlane(w << 6);

  float qr[8];
  {
    const float4* xp = (const float4*)(x + (size_t)(mbase + tok) * 512);
    const float4 x0 = xp[0], x1 = xp[1];
    const float4* tp = (const float4*)theta;
    const float4 t0 = tp[0], t1 = tp[1];
    qr[0] = cosf(x0.x) * cosf(t0.x);  qr[1] = cosf(x0.y) * cosf(t0.y);
    qr[2] = cosf(x0.z) * cosf(t0.z);  qr[3] = cosf(x0.w) * cosf(t0.w);
    qr[4] = cosf(x1.x) * cosf(t1.x);  qr[5] = cosf(x1.y) * cosf(t1.y);
    qr[6] = cosf(x1.z) * cosf(t1.z);  qr[7] = cosf(x1.w) * cosf(t1.w);
  }

#pragma unroll 2
  for (int i = 0; i < 64; ++i) {
    const int oct = obase + i;
    const int f0 = oct << 3;
    const float* __restrict__ bp = b1 + f0;
    u16x8 h8;
#pragma unroll
    for (int r = 0; r < 8; ++r) {
      const float* __restrict__ wp = W1 + ((f0 + r) << 3);   // wave-uniform
      float s = bp[r];
      s = fmaf(qr[0], wp[0], s); s = fmaf(qr[1], wp[1], s);
      s = fmaf(qr[2], wp[2], s); s = fmaf(qr[3], wp[3], s);
      s = fmaf(qr[4], wp[4], s); s = fmaf(qr[5], wp[5], s);
      s = fmaf(qr[6], wp[6], s); s = fmaf(qr[7], wp[7], s);
      h8[r] = f2bf_rne(fmaxf(s, 0.f));
    }
    *(u16x8*)(Hws + (((size_t)oct * chunkM + tok) << 3)) = h8;   // 1KB/wave-inst
  }
}

// ---- layer 2: out = H @ W2^T + b2.  M=chunkM N=512 K=2048 bf16 MFMA ----
// BM=BN=128 BK=64, 256 thr (4 waves 2x2), wave tile 64x64 = 4x4 16x16x32 frags.
// LDS 64KB: A 2x16KB + B 2x16KB dbuf -> 2 blocks/CU. Pre-swizzled GLDS sources,
// XOR-swizzled ds_reads (zero conflicts). XCD swizzle: 4 nt-siblings same XCD.
__global__ __launch_bounds__(256, 2) void k_gemm(
    const u16* __restrict__ Hws, const u16* __restrict__ w2arr,
    const float* __restrict__ b2, float* __restrict__ out,
    int mbase, int chunkM, int qper)   // qper = nblocks/8 (multiple of 4)
{
  __shared__ __align__(16) char smem[65536];
  char* sA0 = smem;
  char* sA1 = smem + 16384;
  char* sB0 = smem + 32768;
  char* sB1 = smem + 49152;

  const int lane = threadIdx.x & 63;
  const int wid  = threadIdx.x >> 6;

  // bijective XCD swizzle: vb = xcd*qper + k; siblings (4 nt of one mt) same XCD
  const int vb = (blockIdx.x & 7) * qper + (blockIdx.x >> 3);
  const int mt = vb >> 2;
  const int nt = vb & 3;

  const int wr = wid >> 1, wc = wid & 1;
  const int l15 = lane & 15;
  const int kq  = lane >> 4;

  // A-stage per-lane source constants: LDS slot (row = c*8 + (l>>3), p = l&7)
  // holds data octet o' = p ^ (row&7) = (l&7) ^ ((l>>3)&7)  (c adds multiples of 8)
  const int op = (lane & 7) ^ ((lane >> 3) & 7);
  const char* asrc0 = (const char*)Hws +
      ((((size_t)op * chunkM + ((size_t)mt << 7) + (lane >> 3)) << 4));
  const size_t akp = ((size_t)chunkM << 7);          // per-kp byte step (8 octet planes)

  f32x4 acc[4][4];
#pragma unroll
  for (int i = 0; i < 4; ++i)
#pragma unroll
    for (int j = 0; j < 4; ++j) acc[i][j] = (f32x4){0.f, 0.f, 0.f, 0.f};

  auto stageA = [&](int kt, char* dst) {
    const char* src = asrc0 + (size_t)kt * akp;
#pragma unroll
    for (int i = 0; i < 4; ++i) {
      const int c = (i << 2) | wid;                  // 16 chunks of 1KB
      GLDS16(src + c * 128, dst + (c << 10));        // row += 8 per chunk
    }
  };
  auto stageB = [&](int kt, char* dst) {
    const char* src = (const char*)w2arr + ((size_t)((nt << 5) + kt) << 14);
#pragma unroll
    for (int i = 0; i < 4; ++i) {
      const int off = ((i << 2) | wid) << 10;
      GLDS16(src + off + lane * 16, dst + off);
    }
  };

  stageA(0, sA0);
  stageB(0, sB0);
  __syncthreads();   // drains vmcnt

  for (int kp = 0; kp < 32; ++kp) {
    char* sAc = (kp & 1) ? sA1 : sA0;
    char* sAn = (kp & 1) ? sA0 : sA1;
    char* sBc = (kp & 1) ? sB1 : sB0;
    char* sBn = (kp & 1) ? sB0 : sB1;
    if (kp < 31) {
      stageA(kp + 1, sAn);          // lands under MFMA below
      stageB(kp + 1, sBn);
    }
    __builtin_amdgcn_s_setprio(1);
#pragma unroll
    for (int ks = 0; ks < 2; ++ks) {
      const int o = (ks << 2) | kq;      // octet 0..7
      bf16x8 ah[4];
#pragma unroll
      for (int mi = 0; mi < 4; ++mi) {
        const int arow = (wr << 6) | (mi << 4) | l15;
        ah[mi] = *(const bf16x8*)(sAc + (arow << 7) + ((o ^ (arow & 7)) << 4));
      }
#pragma unroll
      for (int ni = 0; ni < 4; ++ni) {
        const int bcol = (wc << 6) | (ni << 4) | l15;
        const bf16x8 bh = *(const bf16x8*)(sBc + (bcol << 7) + ((o ^ (bcol & 7)) << 4));
#pragma unroll
        for (int mi = 0; mi < 4; ++mi)
          acc[mi][ni] = __builtin_amdgcn_mfma_f32_16x16x32_bf16(ah[mi], bh, acc[mi][ni], 0, 0, 0);
      }
    }
    __builtin_amdgcn_s_setprio(0);
    __syncthreads();                 // next-tile GLDS landed; this-tile reads done
  }

  // epilogue: 16x16 C/D layout col=lane&15, row=(lane>>4)*4+r (m89-verified)
#pragma unroll
  for (int ni = 0; ni < 4; ++ni) {
    const int col = (nt << 7) | (wc << 6) | (ni << 4) | l15;
    const float bv = b2[col];
#pragma unroll
    for (int mi = 0; mi < 4; ++mi) {
      const int row0 = mbase + (mt << 7) + ((wr << 6) | (mi << 4) | (kq << 2));
      float* op2 = out + (size_t)row0 * 512 + col;
#pragma unroll
      for (int r = 0; r < 4; ++r)
        op2[(size_t)r * 512] = acc[mi][ni][r] + bv;
    }
  }
}

extern "C" void kernel_launch(void* const* d_in, const int* in_sizes, int n_in,
                              void* d_out, int out_size, void* d_ws, size_t ws_size,
                              hipStream_t stream) {
  const float* x     = (const float*)d_in[0];
  const float* theta = (const float*)d_in[1];
  const float* W1    = (const float*)d_in[2];
  const float* b1    = (const float*)d_in[3];
  const float* W2    = (const float*)d_in[4];
  const float* b2    = (const float*)d_in[5];
  float* out = (float*)d_out;

  const int M = in_sizes[0] / 512;                 // 32768 tokens

  u16* w2arr = (u16*)d_ws;                         // 2 MiB
  u16* Hws   = (u16*)((char*)d_ws + (2u << 20));   // H chunk: chunkM*4096 B
  size_t avail = (ws_size > (2u << 20)) ? ws_size - (2u << 20) : 0;

  int chunkM = M;                                  // shrink until H chunk fits
  while (chunkM > 1024 && (size_t)chunkM * 4096 > avail) chunkM >>= 1;

  k_w2prep<<<(1 << 20) / 256, 256, 0, stream>>>(W2, w2arr);
  for (int mb = 0; mb < M; mb += chunkM) {
    k_h<<<chunkM / 64, 256, 0, stream>>>(x, theta, W1, b1, Hws, mb, chunkM);
    const int nb = (chunkM / 128) * 4;
    k_gemm<<<nb, 256, 0, stream>>>(Hws, w2arr, b2, out, mb, chunkM, nb / 8);
  }
}